// Round 16
// baseline (3372.259 us; speedup 1.0000x reference)
//
#include <hip/hip_runtime.h>
#include <hip/hip_bf16.h>

// ============================================================================
// ModelMRM fused forward, round 16: r15 structure at __launch_bounds__(256,3).
// r15 regression = r8/r9 spill repeat: (256,4) caps unified regfile at
// 128/wave -> 64 arch VGPRs -> 4.5GB/launch scratch. RULE (3rd occurrence):
// never set min-waves/EU above what the working set provably fits.
// (256,3) -> 170-reg cap, no spill; with LDS at 27.1KB the HW still grants
// 4 blocks/CU if actual VGPR <= 128 (occupancy follows usage, not the bound).
// Residual-in-registers structure (xr[16], LN via pbuf partials, no xs LDS)
// kept from r15 unchanged.
// ============================================================================

#define NP 32
#define NE 128
#define NSEQ (64 * 256)
#define NMLP 512
#define NDEPTH 4
#define HBS 136     // bf16 LDS row stride (E=128 A-tiles)
#define H1C 264     // bf16 LDS row stride (MLP/dec 256-col chunk)
#define QS  24      // Q/K tile row stride u16
#define PS  40      // P tile row stride u16
#define VST 40      // V^T d-row stride u16
#define PBS 66      // LN partial buffer row stride (f32)

// packed-weight element offsets inside ws (u16 units, after 64B header)
#define QKV_W_OFF 0
#define O_W_OFF   196608
#define M1_W_OFF  262144
#define M2_W_OFF  524288
#define D1_W_OFF  786432
#define W_TOTAL   851968

typedef unsigned short u16;
typedef unsigned int u32;
typedef __attribute__((ext_vector_type(8))) short bf16x8;
typedef __attribute__((ext_vector_type(4))) float f32x4;
typedef __attribute__((ext_vector_type(16))) float f32x16;
#define MFMA16 __builtin_amdgcn_mfma_f32_16x16x32_bf16
#define MFMA32 __builtin_amdgcn_mfma_f32_32x32x16_bf16

__device__ __forceinline__ float b2f(u16 u) {
  union { u32 i; float f; } v; v.i = ((u32)u) << 16; return v.f;
}
__device__ __forceinline__ u16 f2b(float f) {  // RNE via supported API
  __hip_bfloat16 h = __float2bfloat16(f);
  union { __hip_bfloat16 h; u16 u; } v; v.h = h; return v.u;
}
__device__ __forceinline__ u32 pk2(float lo, float hi) {
  return (u32)f2b(lo) | ((u32)f2b(hi) << 16);
}

// gelu, tanh form, 8 VALU ops (|err| <= ~3e-4 abs)
__device__ __forceinline__ float gelu_f(float x) {
  float u = x * x;
  float a2 = x * fmaf(u, 0.07135481627466029f, 1.5957691216057308f);
  float e = __expf(a2);
  float r = __builtin_amdgcn_rcpf(e + 1.0f);
  return fmaf(-x, r, x);
}

struct Args {
  const float *pos, *ctr, *ang;
  const int *sel;
  const float *Wp, *bp, *Wpe1, *bpe1, *Wpe2, *bpe2, *ltype, *mtok;
  const float *Wqkv, *bqkv, *Wo, *bo, *ln1s, *ln1b, *Wm1, *bm1, *Wm2, *bm2;
  const float *ln2s, *ln2b, *lnfs, *lnfb, *Wd1, *bd1, *Wd2, *bd2;
  float* out;
  float* wsf;
  int* wsi;
};

// ---------------------------------------------------------------------------
// Weight pack (validated r4-r15). Columns < scaleN scaled by scale.
// ---------------------------------------------------------------------------
__global__ void pack_w(const float* __restrict__ src, u16* __restrict__ dst,
                       int K, int N, int L, int scaleN, float scale) {
  int id = blockIdx.x * 256 + threadIdx.x;
  int KT = K >> 5, NT = N >> 4;
  int total = L * NT * KT * 64;
  if (id >= total) return;
  int lane = id & 63;
  int rest = id >> 6;
  int kt = rest % KT;
  int rest2 = rest / KT;
  int nt = rest2 % NT;
  int l = rest2 / NT;
  int col = nt * 16 + (lane & 15);
  float sc = (col < scaleN) ? scale : 1.0f;
  const float* s = src + (size_t)l * K * N + (size_t)(kt * 32 + (lane >> 4) * 8) * N + col;
  u16 tmp[8];
#pragma unroll
  for (int j = 0; j < 8; ++j) tmp[j] = f2b(s[(size_t)j * N] * sc);
  ((uint4*)dst)[id] = *(const uint4*)tmp;
}

// GEMM: wave computes 32 x (NTW*16) slab, K=128 (KT=4), A bf16 in LDS.
template <int NTW>
__device__ __forceinline__ void gemm_kt4_b(const u16* __restrict__ hA,
                                           const u16* __restrict__ B, int w,
                                           int lane, const float* __restrict__ bias,
                                           f32x4 (&acc)[NTW][2]) {
  int ar = lane & 15, ac = (lane >> 4) * 8;
  bf16x8 af[8];
#pragma unroll
  for (int kb = 0; kb < 4; ++kb) {
    af[kb]     = *(const bf16x8*)(hA + ar * HBS + kb * 32 + ac);
    af[kb + 4] = *(const bf16x8*)(hA + (ar + 16) * HBS + kb * 32 + ac);
  }
#pragma unroll
  for (int i = 0; i < NTW; ++i) {
    int nt = w + 4 * i;
    const u16* Bp = B + (size_t)nt * 2048 + lane * 8;
    float bb = bias[nt * 16 + ar];
    f32x4 bi = {bb, bb, bb, bb};
    acc[i][0] = bi; acc[i][1] = bi;
#pragma unroll
    for (int kb = 0; kb < 4; ++kb) {
      bf16x8 b = *(const bf16x8*)(Bp + kb * 512);
      acc[i][0] = MFMA16(af[kb], b, acc[i][0], 0, 0, 0);
      acc[i][1] = MFMA16(af[kb + 4], b, acc[i][1], 0, 0, 0);
    }
  }
}

// MLP2/dec2 K-chunk: 256 cols of h1 (kt offset ch*8), A stride H1C, accumulates.
__device__ __forceinline__ void gemm_kt8_acc(const u16* __restrict__ hA,
                                             const u16* __restrict__ B, int ktoff,
                                             int w, int lane, f32x4 (&acc)[2][2]) {
  int ar = lane & 15, ac = (lane >> 4) * 8;
#pragma unroll
  for (int ktl = 0; ktl < 8; ++ktl) {
    bf16x8 a0 = *(const bf16x8*)(hA + ar * H1C + ktl * 32 + ac);
    bf16x8 a1 = *(const bf16x8*)(hA + (ar + 16) * H1C + ktl * 32 + ac);
#pragma unroll
    for (int i = 0; i < 2; ++i) {
      int nt = w + 4 * i;
      bf16x8 b = *(const bf16x8*)(B + (size_t)nt * 8192 + (size_t)(ktoff + ktl) * 512 + lane * 8);
      acc[i][0] = MFMA16(a0, b, acc[i][0], 0, 0, 0);
      acc[i][1] = MFMA16(a1, b, acc[i][1], 0, 0, 0);
    }
  }
}

__global__ __launch_bounds__(256, 3) void mrm_main_mfma(Args a, const u16* __restrict__ wsW) {
  __shared__ __align__(16) u16 hbf[32 * HBS];        // bf16 A-tiles, 8704 B
  __shared__ __align__(16) u16 uniu[8704];           // 17408 B union
  __shared__ float posb[64];
  __shared__ float mrow[32], vrow[32];
  __shared__ int selv[32];
  __shared__ float lacc;

  // union views:
  //   attn:  qb2 [4][32][QS] @0, kb2 @3072, vb2 [4][16][VST] @6144 -> 8704 u16
  //   LN:    pbufS f32[32][PBS] @byte0, pbufQ @byte8448 -> 16896 B
  //   mlp:   h1c u16[32][H1C] @0 -> 16896 B
  //   prol:  tvec f32[128] @0, pvec f32[128] @256
  u16* h1c = uniu;
  float* pbufS = (float*)uniu;
  float* pbufQ = (float*)(uniu + 4224);
  float* tvec = (float*)uniu;
  float* pvec = (float*)uniu + 128;

  const int s = blockIdx.x;
  const int t = threadIdx.x;
  const int w = t >> 6, lane = t & 63;
  const int cr = lane & 15, rq = (lane >> 4) * 4;
  const int l15 = lane & 15, gl = lane >> 4;
  const int l31 = lane & 31, hi5 = lane >> 5;

  if (t == 0) lacc = 0.f;
  if (t < 32) selv[t] = a.sel[s * NP + t];
  if (t < 64) posb[t] = a.pos[s * 64 + t];

  const float cx = a.ctr[s * 2 + 0];
  const float cy = a.ctr[s * 2 + 1];
  const float an = a.ang[s];
  const float ca = __cosf(an), sa = __sinf(an);

  // ---- positional embedding ----
  if (t < 128) {
    float accp = a.bpe1[t] + cx * a.Wpe1[t] + cy * a.Wpe1[128 + t]
               + ca * a.Wpe1[256 + t] + sa * a.Wpe1[384 + t];
    tvec[t] = gelu_f(accp);
  }
  __syncthreads();
  if (t < 128) {
    float accp = a.bpe2[t];
    for (int e = 0; e < 128; ++e) accp += tvec[e] * a.Wpe2[e * 128 + t];
    pvec[t] = accp;
  }
  __syncthreads();

  // ---- token build -> xr regs: xr[h*8+i*4+j] = tok[rq+j+16h][(w+4i)*16+cr]
  float xr[16];
  {
    float wpn[2], wpn2[2], addc[2], mtv[2];
#pragma unroll
    for (int i = 0; i < 2; ++i) {
      int n = (w + 4 * i) * 16 + cr;
      wpn[i] = a.Wp[n];
      wpn2[i] = a.Wp[128 + n];
      addc[i] = a.bp[n] + pvec[n] + a.ltype[n];
      mtv[i] = a.mtok[n];
    }
#pragma unroll
    for (int h = 0; h < 2; ++h)
#pragma unroll
      for (int j = 0; j < 4; ++j) {
        int p = rq + j + 16 * h;
        float px = posb[p * 2 + 0] - cx;
        float py = posb[p * 2 + 1] - cy;
        bool mk = selv[p] != 0;
#pragma unroll
        for (int i = 0; i < 2; ++i)
          xr[h * 8 + i * 4 + j] = mk ? mtv[i] : fmaf(px, wpn[i], fmaf(py, wpn2[i], addc[i]));
      }
  }
  __syncthreads();   // pvec reads done before pbuf overwrites uniu

  u16* qb2 = uniu + w * 768;            // this wave's Q tile / P rows 0-15
  u16* kb2 = uniu + 3072 + w * 768;     // this wave's K tile / P rows 16-31
  u16* vb2 = uniu + 6144 + w * 640;     // this wave's V^T tile

  // LN from registers: partials -> pbuf -> stats -> normalize regs -> hbf
#define LN_REG(GAM, BET)                                                       \
  {                                                                            \
    _Pragma("unroll")                                                          \
    for (int h = 0; h < 2; ++h)                                                \
      _Pragma("unroll")                                                        \
      for (int j = 0; j < 4; ++j) {                                            \
        float x0 = xr[h * 8 + j], x1 = xr[h * 8 + 4 + j];                      \
        int row = rq + j + 16 * h;                                             \
        pbufS[row * PBS + w * 16 + cr] = x0 + x1;                              \
        pbufQ[row * PBS + w * 16 + cr] = x0 * x0 + x1 * x1;                    \
      }                                                                        \
    __syncthreads();                                                           \
    {                                                                          \
      int p = t >> 3, j8 = t & 7;                                              \
      const float* bs = pbufS + p * PBS + j8 * 8;                              \
      const float* bq = pbufQ + p * PBS + j8 * 8;                              \
      float sum = 0.f, sq = 0.f;                                               \
      _Pragma("unroll")                                                        \
      for (int k = 0; k < 8; ++k) { sum += bs[k]; sq += bq[k]; }               \
      _Pragma("unroll")                                                        \
      for (int o = 1; o < 8; o <<= 1) {                                        \
        sum += __shfl_xor(sum, o); sq += __shfl_xor(sq, o);                    \
      }                                                                        \
      if (j8 == 0) {                                                           \
        float m = sum * 0.0078125f;                                            \
        mrow[p] = m;                                                           \
        vrow[p] = sq * 0.0078125f - m * m;                                     \
      }                                                                        \
    }                                                                          \
    __syncthreads();                                                           \
    {                                                                          \
      float gv[2], bv[2];                                                      \
      _Pragma("unroll")                                                        \
      for (int i = 0; i < 2; ++i) {                                            \
        int n = (w + 4 * i) * 16 + cr;                                         \
        gv[i] = (GAM)[n]; bv[i] = (BET)[n];                                    \
      }                                                                        \
      _Pragma("unroll")                                                        \
      for (int h = 0; h < 2; ++h)                                              \
        _Pragma("unroll")                                                      \
        for (int j = 0; j < 4; ++j) {                                          \
          int row = rq + j + 16 * h;                                           \
          float m = mrow[row], rs = rsqrtf(vrow[row] + 1e-5f);                 \
          _Pragma("unroll")                                                    \
          for (int i = 0; i < 2; ++i) {                                        \
            int n = (w + 4 * i) * 16 + cr;                                     \
            float hv = fmaf((xr[h * 8 + i * 4 + j] - m) * rs, gv[i], bv[i]);   \
            hbf[row * HBS + n] = f2b(hv);                                      \
          }                                                                    \
        }                                                                      \
    }                                                                          \
    __syncthreads();                                                           \
  }

  // ---- layers ----
  for (int li = 0; li < NDEPTH; ++li) {
    const u16* qkvW = wsW + QKV_W_OFF + li * 49152;
    const u16* oW   = wsW + O_W_OFF   + li * 16384;
    const u16* m1W  = wsW + M1_W_OFF  + li * 65536;
    const u16* m2W  = wsW + M2_W_OFF  + li * 65536;
    const float* bqkv_i = a.bqkv + li * 384;
    const float* bo_i   = a.bo + li * NE;
    const float* bm1_i  = a.bm1 + li * NMLP;
    const float* bm2_i  = a.bm2 + li * NE;

    LN_REG(a.ln1s + li * NE, a.ln1b + li * NE);

    // ---- 2 passes: QKV (1 head/wave) + attention; O deferred in opk regs ----
    u32 opk[2][2][2];
#pragma unroll
    for (int p = 0; p < 2; ++p) {
      const int hh = 4 * p + w;
      f32x4 acc[3][2];
      {
        int ar = lane & 15, ac = (lane >> 4) * 8;
        bf16x8 af[8];
#pragma unroll
        for (int kb = 0; kb < 4; ++kb) {
          af[kb]     = *(const bf16x8*)(hbf + ar * HBS + kb * 32 + ac);
          af[kb + 4] = *(const bf16x8*)(hbf + (ar + 16) * HBS + kb * 32 + ac);
        }
#pragma unroll
        for (int i = 0; i < 3; ++i) {
          int nt = i * 8 + hh;
          const u16* Bp = qkvW + (size_t)nt * 2048 + lane * 8;
          float bb = bqkv_i[nt * 16 + ar];
          if (i == 0) bb *= 0.25f;
          f32x4 bi = {bb, bb, bb, bb};
          acc[i][0] = bi; acc[i][1] = bi;
#pragma unroll
          for (int kb = 0; kb < 4; ++kb) {
            bf16x8 b = *(const bf16x8*)(Bp + kb * 512);
            acc[i][0] = MFMA16(af[kb], b, acc[i][0], 0, 0, 0);
            acc[i][1] = MFMA16(af[kb + 4], b, acc[i][1], 0, 0, 0);
          }
        }
      }
      {
#pragma unroll
        for (int j = 0; j < 4; ++j) {
          qb2[(rq + j) * QS + cr]      = f2b(acc[0][0][j]);
          qb2[(rq + j + 16) * QS + cr] = f2b(acc[0][1][j]);
          kb2[(rq + j) * QS + cr]      = f2b(acc[1][0][j]);
          kb2[(rq + j + 16) * QS + cr] = f2b(acc[1][1][j]);
        }
        u32* vbw = (u32*)vb2 + cr * 20 + (rq >> 1);
        vbw[0] = pk2(acc[2][0][0], acc[2][0][1]);
        vbw[1] = pk2(acc[2][0][2], acc[2][0][3]);
        vbw[8] = pk2(acc[2][1][0], acc[2][1][1]);
        vbw[9] = pk2(acc[2][1][2], acc[2][1][3]);
      }
      {
        bf16x8 kf = *(const bf16x8*)(kb2 + l31 * QS + hi5 * 8);
        bf16x8 qf = *(const bf16x8*)(qb2 + l31 * QS + hi5 * 8);
        f32x16 z16 = {0.f,0.f,0.f,0.f,0.f,0.f,0.f,0.f,0.f,0.f,0.f,0.f,0.f,0.f,0.f,0.f};
        f32x16 S = MFMA32(kf, qf, z16, 0, 0, 0);
        float m01 = fmaxf(S[0], S[1]),   m23 = fmaxf(S[2], S[3]);
        float m45 = fmaxf(S[4], S[5]),   m67 = fmaxf(S[6], S[7]);
        float m89 = fmaxf(S[8], S[9]),   mab = fmaxf(S[10], S[11]);
        float mcd = fmaxf(S[12], S[13]), mef = fmaxf(S[14], S[15]);
        float mx = fmaxf(fmaxf(fmaxf(m01, m23), fmaxf(m45, m67)),
                         fmaxf(fmaxf(m89, mab), fmaxf(mcd, mef)));
        mx = fmaxf(mx, __shfl_xor(mx, 32));
#pragma unroll
        for (int r = 0; r < 16; ++r) S[r] = __expf(S[r] - mx);
        float sum = ((S[0] + S[1]) + (S[2] + S[3])) + ((S[4] + S[5]) + (S[6] + S[7]))
                  + ((S[8] + S[9]) + (S[10] + S[11])) + ((S[12] + S[13]) + (S[14] + S[15]));
        sum += __shfl_xor(sum, 32);
        float inv = __builtin_amdgcn_rcpf(sum);
        u16* pb = ((l31 < 16) ? qb2 : kb2) + (l31 & 15) * PS;
#pragma unroll
        for (int i2 = 0; i2 < 8; ++i2) {
          int key0 = ((2 * i2) & 3) + 8 * (i2 >> 1) + 4 * hi5;
          *(u32*)(pb + key0) = pk2(S[2 * i2] * inv, S[2 * i2 + 1] * inv);
        }
        bf16x8 vf = *(const bf16x8*)(vb2 + l15 * VST + gl * 8);
        const f32x4 z = {0.f, 0.f, 0.f, 0.f};
#pragma unroll
        for (int qt = 0; qt < 2; ++qt) {
          bf16x8 pa = *(const bf16x8*)(((qt == 0) ? qb2 : kb2) + l15 * PS + gl * 8);
          f32x4 o = MFMA16(pa, vf, z, 0, 0, 0);
          opk[p][qt][0] = pk2(o[0], o[1]);
          opk[p][qt][1] = pk2(o[2], o[3]);
        }
      }
    }
    __syncthreads();   // all waves done READING hbf (af) before flush
#pragma unroll
    for (int p = 0; p < 2; ++p) {
      const int hh = 4 * p + w;
#pragma unroll
      for (int qt = 0; qt < 2; ++qt) {
        u16* dst = hbf + (qt * 16 + gl * 4) * HBS + hh * 16 + l15;
        dst[0 * HBS] = (u16)opk[p][qt][0];
        dst[1 * HBS] = (u16)(opk[p][qt][0] >> 16);
        dst[2 * HBS] = (u16)opk[p][qt][1];
        dst[3 * HBS] = (u16)(opk[p][qt][1] >> 16);
      }
    }
    __syncthreads();

    // ---- proj: attn_out(hbf) @ Wo -> xr += (register residual) ----
    {
      f32x4 acc[2][2];
      gemm_kt4_b<2>(hbf, oW, w, lane, bo_i, acc);
#pragma unroll
      for (int i = 0; i < 2; ++i)
#pragma unroll
        for (int j = 0; j < 4; ++j) {
          xr[0 + i * 4 + j] += acc[i][0][j];
          xr[8 + i * 4 + j] += acc[i][1][j];
        }
    }

    LN_REG(a.ln2s + li * NE, a.ln2b + li * NE);

    // ---- MLP, 2 chunks of 256 cols; residual add into xr ----
    {
      f32x4 acc2[2][2];
#pragma unroll
      for (int i = 0; i < 2; ++i) {
        float bb = bm2_i[(w + 4 * i) * 16 + cr];
        f32x4 bi = {bb, bb, bb, bb};
        acc2[i][0] = bi; acc2[i][1] = bi;
      }
#pragma unroll
      for (int ch = 0; ch < 2; ++ch) {
        {
          f32x4 acc[4][2];
          gemm_kt4_b<4>(hbf, m1W + ch * 32768, w, lane, bm1_i + ch * 256, acc);
#pragma unroll
          for (int i = 0; i < 4; ++i) {
            int nl = (w + 4 * i) * 16 + cr;
#pragma unroll
            for (int j = 0; j < 4; ++j) {
              h1c[(rq + j) * H1C + nl]      = f2b(gelu_f(acc[i][0][j]));
              h1c[(rq + j + 16) * H1C + nl] = f2b(gelu_f(acc[i][1][j]));
            }
          }
        }
        __syncthreads();
        gemm_kt8_acc(h1c, m2W, ch * 8, w, lane, acc2);
        __syncthreads();
      }
#pragma unroll
      for (int i = 0; i < 2; ++i)
#pragma unroll
        for (int j = 0; j < 4; ++j) {
          xr[0 + i * 4 + j] += acc2[i][0][j];
          xr[8 + i * 4 + j] += acc2[i][1][j];
        }
    }
  }

  // ---- final LN -> hbf ----
  LN_REG(a.lnfs, a.lnfb);

  // ---- decoder, 2 chunks of 256 (Wd2 read from global: L1-broadcast) ----
  float yacc = 0.f;
  const int pdec = t >> 3, dd2 = (t >> 2) & 1, q4 = t & 3;
#pragma unroll
  for (int ch = 0; ch < 2; ++ch) {
    {
      f32x4 acc[4][2];
      gemm_kt4_b<4>(hbf, wsW + D1_W_OFF + ch * 32768, w, lane, a.bd1 + ch * 256, acc);
#pragma unroll
      for (int i = 0; i < 4; ++i) {
        int nl = (w + 4 * i) * 16 + cr;
#pragma unroll
        for (int j = 0; j < 4; ++j) {
          h1c[(rq + j) * H1C + nl]      = f2b(fmaxf(acc[i][0][j], 0.f));
          h1c[(rq + j + 16) * H1C + nl] = f2b(fmaxf(acc[i][1][j], 0.f));
        }
      }
    }
    __syncthreads();
    {
      const u16* hrow = h1c + pdec * H1C + q4 * 64;
      const float* wp = a.Wd2 + (ch * 256 + q4 * 64) * 2 + dd2;
#pragma unroll
      for (int k8 = 0; k8 < 8; ++k8) {
        bf16x8 hv = *(const bf16x8*)(hrow + k8 * 8);
#pragma unroll
        for (int jj = 0; jj < 8; ++jj)
          yacc += b2f((u16)hv[jj]) * wp[(k8 * 8 + jj) * 2];
      }
    }
    __syncthreads();
  }

  // ---- y write + loss partial ----
  {
    yacc += __shfl_xor(yacc, 1);
    yacc += __shfl_xor(yacc, 2);
    if (q4 == 0) {
      float y = yacc + a.bd2[dd2];
      a.out[1 + (s * NP + pdec) * 2 + dd2] = y;
      float lnm = posb[pdec * 2 + dd2] - (dd2 ? cy : cx);
      float d = y - lnm;
      if (selv[pdec] != 0) atomicAdd(&lacc, d * d);
    }
  }
  __syncthreads();
  if (t == 0) {
    atomicAdd(a.wsf, lacc);
    int cnt = 0;
#pragma unroll
    for (int p = 0; p < NP; ++p) cnt += (selv[p] != 0) ? 1 : 0;
    atomicAdd(a.wsi, cnt);
  }
}

__global__ void mrm_fin(const float* ws, float* out) {
  float num = ws[0];
  int cnt = ((const int*)ws)[1];
  float den = fmaxf((float)cnt * 2.0f, 1.0f);
  out[0] = num / den;
}

extern "C" void kernel_launch(void* const* d_in, const int* in_sizes, int n_in,
                              void* d_out, int out_size, void* d_ws, size_t ws_size,
                              hipStream_t stream) {
  (void)in_sizes; (void)n_in; (void)out_size; (void)ws_size;
  Args a;
  a.pos   = (const float*)d_in[0];
  a.ctr   = (const float*)d_in[1];
  a.ang   = (const float*)d_in[2];
  a.sel   = (const int*)d_in[4];
  a.Wp    = (const float*)d_in[5];
  a.bp    = (const float*)d_in[6];
  a.Wpe1  = (const float*)d_in[7];
  a.bpe1  = (const float*)d_in[8];
  a.Wpe2  = (const float*)d_in[9];
  a.bpe2  = (const float*)d_in[10];
  a.ltype = (const float*)d_in[11];
  a.mtok  = (const float*)d_in[12];
  a.Wqkv  = (const float*)d_in[13];
  a.bqkv  = (const float*)d_in[14];
  a.Wo    = (const float*)d_in[15];
  a.bo    = (const float*)d_in[16];
  a.ln1s  = (const float*)d_in[17];
  a.ln1b  = (const float*)d_in[18];
  a.Wm1   = (const float*)d_in[19];
  a.bm1   = (const float*)d_in[20];
  a.Wm2   = (const float*)d_in[21];
  a.bm2   = (const float*)d_in[22];
  a.ln2s  = (const float*)d_in[23];
  a.ln2b  = (const float*)d_in[24];
  a.lnfs  = (const float*)d_in[25];
  a.lnfb  = (const float*)d_in[26];
  a.Wd1   = (const float*)d_in[27];
  a.bd1   = (const float*)d_in[28];
  a.Wd2   = (const float*)d_in[29];
  a.bd2   = (const float*)d_in[30];
  a.out   = (float*)d_out;
  a.wsf   = (float*)d_ws;
  a.wsi   = ((int*)d_ws) + 1;

  hipMemsetAsync(d_ws, 0, 8, stream);
  u16* wsW = (u16*)((char*)d_ws + 64);
  pack_w<<<dim3(96),  dim3(256), 0, stream>>>(a.Wqkv, wsW + QKV_W_OFF, 128, 384, 4, 128, 0.25f);
  pack_w<<<dim3(32),  dim3(256), 0, stream>>>(a.Wo,   wsW + O_W_OFF,   128, 128, 4, 0, 1.f);
  pack_w<<<dim3(128), dim3(256), 0, stream>>>(a.Wm1,  wsW + M1_W_OFF,  128, 512, 4, 0, 1.f);
  pack_w<<<dim3(128), dim3(256), 0, stream>>>(a.Wm2,  wsW + M2_W_OFF,  512, 128, 4, 0, 1.f);
  pack_w<<<dim3(32),  dim3(256), 0, stream>>>(a.Wd1,  wsW + D1_W_OFF,  128, 512, 1, 0, 1.f);
  mrm_main_mfma<<<dim3(NSEQ), dim3(256), 0, stream>>>(a, wsW);
  mrm_fin<<<dim3(1), dim3(1), 0, stream>>>((const float*)d_ws, (float*)d_out);
}

// Round 17
// 2109.217 us; speedup vs baseline: 1.5988x; 1.5988x over previous
//
#include <hip/hip_runtime.h>
#include <hip/hip_bf16.h>

// ============================================================================
// ModelMRM fused forward, round 17: REVERT to r14 (best verified: 2135us).
// r15/r16 falsified the residual-in-registers branch: xr[16] + MFMA working
// set exceeds what the allocator keeps resident (xr demoted to scratch even
// at the 170-reg cap; WRITE_SIZE 433MB). Residual stays in LDS (xs).
// r14 = r12 strides/structure + tanh-gelu + rcpf softmax + API f2b (cvt_pk)
// + reg-cached LN + tree reductions. LDS 47.1KB -> 3 blocks/CU, no spill.
// ============================================================================

#define NP 32
#define NE 128
#define NSEQ (64 * 256)
#define NMLP 512
#define NDEPTH 4
#define LST 132     // f32 LDS row stride (residual)
#define HBS 136     // bf16 LDS row stride (E=128 A-tiles)
#define H1C 264     // bf16 LDS row stride (MLP/dec 256-col chunk)
#define QS  24      // Q/K tile row stride u16
#define PS  40      // P tile row stride u16
#define VST 40      // V^T d-row stride u16

// packed-weight element offsets inside ws (u16 units, after 64B header)
#define QKV_W_OFF 0
#define O_W_OFF   196608
#define M1_W_OFF  262144
#define M2_W_OFF  524288
#define D1_W_OFF  786432
#define W_TOTAL   851968

typedef unsigned short u16;
typedef unsigned int u32;
typedef __attribute__((ext_vector_type(8))) short bf16x8;
typedef __attribute__((ext_vector_type(4))) float f32x4;
typedef __attribute__((ext_vector_type(16))) float f32x16;
#define MFMA16 __builtin_amdgcn_mfma_f32_16x16x32_bf16
#define MFMA32 __builtin_amdgcn_mfma_f32_32x32x16_bf16

__device__ __forceinline__ float b2f(u16 u) {
  union { u32 i; float f; } v; v.i = ((u32)u) << 16; return v.f;
}
__device__ __forceinline__ u16 f2b(float f) {  // RNE via supported API
  __hip_bfloat16 h = __float2bfloat16(f);
  union { __hip_bfloat16 h; u16 u; } v; v.h = h; return v.u;
}
__device__ __forceinline__ u32 pk2(float lo, float hi) {
  return (u32)f2b(lo) | ((u32)f2b(hi) << 16);   // compiler fuses to cvt_pk
}

// gelu, tanh form, 8 VALU ops (|err| <= ~3e-4 abs)
__device__ __forceinline__ float gelu_f(float x) {
  float u = x * x;
  float a2 = x * fmaf(u, 0.07135481627466029f, 1.5957691216057308f);
  float e = __expf(a2);
  float r = __builtin_amdgcn_rcpf(e + 1.0f);
  return fmaf(-x, r, x);
}

struct Args {
  const float *pos, *ctr, *ang;
  const int *sel;
  const float *Wp, *bp, *Wpe1, *bpe1, *Wpe2, *bpe2, *ltype, *mtok;
  const float *Wqkv, *bqkv, *Wo, *bo, *ln1s, *ln1b, *Wm1, *bm1, *Wm2, *bm2;
  const float *ln2s, *ln2b, *lnfs, *lnfb, *Wd1, *bd1, *Wd2, *bd2;
  float* out;
  float* wsf;
  int* wsi;
};

// ---------------------------------------------------------------------------
// Weight pack (validated r4-r14). Columns < scaleN scaled by scale.
// ---------------------------------------------------------------------------
__global__ void pack_w(const float* __restrict__ src, u16* __restrict__ dst,
                       int K, int N, int L, int scaleN, float scale) {
  int id = blockIdx.x * 256 + threadIdx.x;
  int KT = K >> 5, NT = N >> 4;
  int total = L * NT * KT * 64;
  if (id >= total) return;
  int lane = id & 63;
  int rest = id >> 6;
  int kt = rest % KT;
  int rest2 = rest / KT;
  int nt = rest2 % NT;
  int l = rest2 / NT;
  int col = nt * 16 + (lane & 15);
  float sc = (col < scaleN) ? scale : 1.0f;
  const float* s = src + (size_t)l * K * N + (size_t)(kt * 32 + (lane >> 4) * 8) * N + col;
  u16 tmp[8];
#pragma unroll
  for (int j = 0; j < 8; ++j) tmp[j] = f2b(s[(size_t)j * N] * sc);
  ((uint4*)dst)[id] = *(const uint4*)tmp;
}

// GEMM: wave computes 32 x (NTW*16) slab, K=128 (KT=4), A bf16 in LDS.
template <int NTW>
__device__ __forceinline__ void gemm_kt4_b(const u16* __restrict__ hA,
                                           const u16* __restrict__ B, int w,
                                           int lane, const float* __restrict__ bias,
                                           f32x4 (&acc)[NTW][2]) {
  int ar = lane & 15, ac = (lane >> 4) * 8;
  bf16x8 af[8];
#pragma unroll
  for (int kb = 0; kb < 4; ++kb) {
    af[kb]     = *(const bf16x8*)(hA + ar * HBS + kb * 32 + ac);
    af[kb + 4] = *(const bf16x8*)(hA + (ar + 16) * HBS + kb * 32 + ac);
  }
#pragma unroll
  for (int i = 0; i < NTW; ++i) {
    int nt = w + 4 * i;
    const u16* Bp = B + (size_t)nt * 2048 + lane * 8;
    float bb = bias[nt * 16 + ar];
    f32x4 bi = {bb, bb, bb, bb};
    acc[i][0] = bi; acc[i][1] = bi;
#pragma unroll
    for (int kb = 0; kb < 4; ++kb) {
      bf16x8 b = *(const bf16x8*)(Bp + kb * 512);
      acc[i][0] = MFMA16(af[kb], b, acc[i][0], 0, 0, 0);
      acc[i][1] = MFMA16(af[kb + 4], b, acc[i][1], 0, 0, 0);
    }
  }
}

// MLP2/dec2 K-chunk: 256 cols of h1 (kt offset ch*8), A stride H1C, accumulates.
__device__ __forceinline__ void gemm_kt8_acc(const u16* __restrict__ hA,
                                             const u16* __restrict__ B, int ktoff,
                                             int w, int lane, f32x4 (&acc)[2][2]) {
  int ar = lane & 15, ac = (lane >> 4) * 8;
#pragma unroll
  for (int ktl = 0; ktl < 8; ++ktl) {
    bf16x8 a0 = *(const bf16x8*)(hA + ar * H1C + ktl * 32 + ac);
    bf16x8 a1 = *(const bf16x8*)(hA + (ar + 16) * H1C + ktl * 32 + ac);
#pragma unroll
    for (int i = 0; i < 2; ++i) {
      int nt = w + 4 * i;
      bf16x8 b = *(const bf16x8*)(B + (size_t)nt * 8192 + (size_t)(ktoff + ktl) * 512 + lane * 8);
      acc[i][0] = MFMA16(a0, b, acc[i][0], 0, 0, 0);
      acc[i][1] = MFMA16(a1, b, acc[i][1], 0, 0, 0);
    }
  }
}

// LN(src f32 [32][LST]) * gam + bet -> dst bf16 [32][HBS]
// Row values cached in registers across the barrier (no LDS re-read).
__device__ __forceinline__ void layer_norm_bf(const float* __restrict__ src,
                                              u16* __restrict__ dst,
                                              const float* gam, const float* bet,
                                              int t, float* mrow, float* vrow) {
  int p = t >> 3, j0 = (t & 7) * 16;
  const float* row = src + p * LST + j0;
  float4 vr0 = ((const float4*)row)[0];
  float4 vr1 = ((const float4*)row)[1];
  float4 vr2 = ((const float4*)row)[2];
  float4 vr3 = ((const float4*)row)[3];
  float sum = ((vr0.x + vr0.y) + (vr0.z + vr0.w)) + ((vr1.x + vr1.y) + (vr1.z + vr1.w))
            + ((vr2.x + vr2.y) + (vr2.z + vr2.w)) + ((vr3.x + vr3.y) + (vr3.z + vr3.w));
  float sq = ((vr0.x*vr0.x + vr0.y*vr0.y) + (vr0.z*vr0.z + vr0.w*vr0.w))
           + ((vr1.x*vr1.x + vr1.y*vr1.y) + (vr1.z*vr1.z + vr1.w*vr1.w))
           + ((vr2.x*vr2.x + vr2.y*vr2.y) + (vr2.z*vr2.z + vr2.w*vr2.w))
           + ((vr3.x*vr3.x + vr3.y*vr3.y) + (vr3.z*vr3.z + vr3.w*vr3.w));
#pragma unroll
  for (int o = 1; o < 8; o <<= 1) { sum += __shfl_xor(sum, o); sq += __shfl_xor(sq, o); }
  if ((t & 7) == 0) {
    float m = sum * 0.0078125f;
    mrow[p] = m;
    vrow[p] = sq * 0.0078125f - m * m;
  }
  __syncthreads();
  float m = mrow[p], rs = rsqrtf(vrow[p] + 1e-5f);
  u32 wb[8];
  {
    float4 g = ((const float4*)(gam + j0))[0], b = ((const float4*)(bet + j0))[0];
    wb[0] = pk2(fmaf((vr0.x - m) * rs, g.x, b.x), fmaf((vr0.y - m) * rs, g.y, b.y));
    wb[1] = pk2(fmaf((vr0.z - m) * rs, g.z, b.z), fmaf((vr0.w - m) * rs, g.w, b.w));
  }
  {
    float4 g = ((const float4*)(gam + j0))[1], b = ((const float4*)(bet + j0))[1];
    wb[2] = pk2(fmaf((vr1.x - m) * rs, g.x, b.x), fmaf((vr1.y - m) * rs, g.y, b.y));
    wb[3] = pk2(fmaf((vr1.z - m) * rs, g.z, b.z), fmaf((vr1.w - m) * rs, g.w, b.w));
  }
  {
    float4 g = ((const float4*)(gam + j0))[2], b = ((const float4*)(bet + j0))[2];
    wb[4] = pk2(fmaf((vr2.x - m) * rs, g.x, b.x), fmaf((vr2.y - m) * rs, g.y, b.y));
    wb[5] = pk2(fmaf((vr2.z - m) * rs, g.z, b.z), fmaf((vr2.w - m) * rs, g.w, b.w));
  }
  {
    float4 g = ((const float4*)(gam + j0))[3], b = ((const float4*)(bet + j0))[3];
    wb[6] = pk2(fmaf((vr3.x - m) * rs, g.x, b.x), fmaf((vr3.y - m) * rs, g.y, b.y));
    wb[7] = pk2(fmaf((vr3.z - m) * rs, g.z, b.z), fmaf((vr3.w - m) * rs, g.w, b.w));
  }
  uint4* dp = (uint4*)(dst + p * HBS + j0);
  dp[0] = make_uint4(wb[0], wb[1], wb[2], wb[3]);
  dp[1] = make_uint4(wb[4], wb[5], wb[6], wb[7]);
  __syncthreads();
}

__global__ __launch_bounds__(256, 3) void mrm_main_mfma(Args a, const u16* __restrict__ wsW) {
  __shared__ float xs[32 * LST];                     // residual f32, 16896 B
  __shared__ __align__(16) u16 hbf[32 * HBS];        // bf16 A-tiles, 8704 B
  __shared__ __align__(16) u16 uniu[10496];          // 20992 B union
  __shared__ float mrow[32], vrow[32];
  __shared__ int selv[32];
  __shared__ float lacc;

  u16* h1c = uniu;
  float* wd2s = (float*)(uniu + 8448);
  float* tvec = (float*)uniu;
  float* pvec = (float*)uniu + 128;

  const int s = blockIdx.x;
  const int t = threadIdx.x;
  const int w = t >> 6, lane = t & 63;
  const int cr = lane & 15, rq = (lane >> 4) * 4;
  const int rg = t >> 5, cg = t & 31, r0 = rg * 4, c0 = cg * 4;
  const int l15 = lane & 15, gl = lane >> 4;
  const int l31 = lane & 31, hi5 = lane >> 5;

  if (t == 0) lacc = 0.f;
  if (t < 32) selv[t] = a.sel[s * NP + t];

  const float cx = a.ctr[s * 2 + 0];
  const float cy = a.ctr[s * 2 + 1];
  const float an = a.ang[s];
  const float ca = __cosf(an), sa = __sinf(an);

  // ---- positional embedding ----
  if (t < 128) {
    float accp = a.bpe1[t] + cx * a.Wpe1[t] + cy * a.Wpe1[128 + t]
               + ca * a.Wpe1[256 + t] + sa * a.Wpe1[384 + t];
    tvec[t] = gelu_f(accp);
  }
  __syncthreads();
  if (t < 128) {
    float accp = a.bpe2[t];
    for (int e = 0; e < 128; ++e) accp += tvec[e] * a.Wpe2[e * 128 + t];
    pvec[t] = accp;
  }
  __syncthreads();

  // ---- token build -> xs f32 ----
  {
    float4 w0v = *(const float4*)(a.Wp + c0);
    float4 w1v = *(const float4*)(a.Wp + NE + c0);
    float4 bpv = *(const float4*)(a.bp + c0);
    float4 ltv = *(const float4*)(a.ltype + c0);
    float4 mtv = *(const float4*)(a.mtok + c0);
    float a0 = bpv.x + pvec[c0 + 0] + ltv.x;
    float a1 = bpv.y + pvec[c0 + 1] + ltv.y;
    float a2 = bpv.z + pvec[c0 + 2] + ltv.z;
    float a3 = bpv.w + pvec[c0 + 3] + ltv.w;
#pragma unroll
    for (int rr = 0; rr < 4; ++rr) {
      int p = r0 + rr;
      float px = a.pos[(s * NP + p) * 2 + 0] - cx;
      float py = a.pos[(s * NP + p) * 2 + 1] - cy;
      bool mk = selv[p] != 0;
      float4 o;
      o.x = mk ? mtv.x : (px * w0v.x + py * w1v.x + a0);
      o.y = mk ? mtv.y : (px * w0v.y + py * w1v.y + a1);
      o.z = mk ? mtv.z : (px * w0v.z + py * w1v.z + a2);
      o.w = mk ? mtv.w : (px * w0v.w + py * w1v.w + a3);
      *(float4*)&xs[p * LST + c0] = o;
    }
  }
  __syncthreads();

  u16* qb2 = uniu + w * 768;            // this wave's Q tile / P rows 0-15
  u16* kb2 = uniu + 3072 + w * 768;     // this wave's K tile / P rows 16-31
  u16* vb2 = uniu + 6144 + w * 640;     // this wave's V^T tile

  // ---- layers ----
  for (int li = 0; li < NDEPTH; ++li) {
    const u16* qkvW = wsW + QKV_W_OFF + li * 49152;
    const u16* oW   = wsW + O_W_OFF   + li * 16384;
    const u16* m1W  = wsW + M1_W_OFF  + li * 65536;
    const u16* m2W  = wsW + M2_W_OFF  + li * 65536;
    const float* bqkv_i = a.bqkv + li * 384;
    const float* bo_i   = a.bo + li * NE;
    const float* bm1_i  = a.bm1 + li * NMLP;
    const float* bm2_i  = a.bm2 + li * NE;

    layer_norm_bf(xs, hbf, a.ln1s + li * NE, a.ln1b + li * NE, t, mrow, vrow);

    // ---- 2 passes: QKV (1 head/wave) + attention; O deferred in opk regs ----
    u32 opk[2][2][2];
#pragma unroll
    for (int p = 0; p < 2; ++p) {
      const int hh = 4 * p + w;
      f32x4 acc[3][2];
      {
        int ar = lane & 15, ac = (lane >> 4) * 8;
        bf16x8 af[8];
#pragma unroll
        for (int kb = 0; kb < 4; ++kb) {
          af[kb]     = *(const bf16x8*)(hbf + ar * HBS + kb * 32 + ac);
          af[kb + 4] = *(const bf16x8*)(hbf + (ar + 16) * HBS + kb * 32 + ac);
        }
#pragma unroll
        for (int i = 0; i < 3; ++i) {
          int nt = i * 8 + hh;
          const u16* Bp = qkvW + (size_t)nt * 2048 + lane * 8;
          float bb = bqkv_i[nt * 16 + ar];
          if (i == 0) bb *= 0.25f;
          f32x4 bi = {bb, bb, bb, bb};
          acc[i][0] = bi; acc[i][1] = bi;
#pragma unroll
          for (int kb = 0; kb < 4; ++kb) {
            bf16x8 b = *(const bf16x8*)(Bp + kb * 512);
            acc[i][0] = MFMA16(af[kb], b, acc[i][0], 0, 0, 0);
            acc[i][1] = MFMA16(af[kb + 4], b, acc[i][1], 0, 0, 0);
          }
        }
      }
      {
#pragma unroll
        for (int j = 0; j < 4; ++j) {
          qb2[(rq + j) * QS + cr]      = f2b(acc[0][0][j]);
          qb2[(rq + j + 16) * QS + cr] = f2b(acc[0][1][j]);
          kb2[(rq + j) * QS + cr]      = f2b(acc[1][0][j]);
          kb2[(rq + j + 16) * QS + cr] = f2b(acc[1][1][j]);
        }
        u32* vbw = (u32*)vb2 + cr * 20 + (rq >> 1);
        vbw[0] = pk2(acc[2][0][0], acc[2][0][1]);
        vbw[1] = pk2(acc[2][0][2], acc[2][0][3]);
        vbw[8] = pk2(acc[2][1][0], acc[2][1][1]);
        vbw[9] = pk2(acc[2][1][2], acc[2][1][3]);
      }
      {
        bf16x8 kf = *(const bf16x8*)(kb2 + l31 * QS + hi5 * 8);
        bf16x8 qf = *(const bf16x8*)(qb2 + l31 * QS + hi5 * 8);
        f32x16 z16 = {0.f,0.f,0.f,0.f,0.f,0.f,0.f,0.f,0.f,0.f,0.f,0.f,0.f,0.f,0.f,0.f};
        f32x16 S = MFMA32(kf, qf, z16, 0, 0, 0);
        float m01 = fmaxf(S[0], S[1]),   m23 = fmaxf(S[2], S[3]);
        float m45 = fmaxf(S[4], S[5]),   m67 = fmaxf(S[6], S[7]);
        float m89 = fmaxf(S[8], S[9]),   mab = fmaxf(S[10], S[11]);
        float mcd = fmaxf(S[12], S[13]), mef = fmaxf(S[14], S[15]);
        float mx = fmaxf(fmaxf(fmaxf(m01, m23), fmaxf(m45, m67)),
                         fmaxf(fmaxf(m89, mab), fmaxf(mcd, mef)));
        mx = fmaxf(mx, __shfl_xor(mx, 32));
#pragma unroll
        for (int r = 0; r < 16; ++r) S[r] = __expf(S[r] - mx);
        float sum = ((S[0] + S[1]) + (S[2] + S[3])) + ((S[4] + S[5]) + (S[6] + S[7]))
                  + ((S[8] + S[9]) + (S[10] + S[11])) + ((S[12] + S[13]) + (S[14] + S[15]));
        sum += __shfl_xor(sum, 32);
        float inv = __builtin_amdgcn_rcpf(sum);
        u16* pb = ((l31 < 16) ? qb2 : kb2) + (l31 & 15) * PS;
#pragma unroll
        for (int i2 = 0; i2 < 8; ++i2) {
          int key0 = ((2 * i2) & 3) + 8 * (i2 >> 1) + 4 * hi5;
          *(u32*)(pb + key0) = pk2(S[2 * i2] * inv, S[2 * i2 + 1] * inv);
        }
        bf16x8 vf = *(const bf16x8*)(vb2 + l15 * VST + gl * 8);
        const f32x4 z = {0.f, 0.f, 0.f, 0.f};
#pragma unroll
        for (int qt = 0; qt < 2; ++qt) {
          bf16x8 pa = *(const bf16x8*)(((qt == 0) ? qb2 : kb2) + l15 * PS + gl * 8);
          f32x4 o = MFMA16(pa, vf, z, 0, 0, 0);
          opk[p][qt][0] = pk2(o[0], o[1]);
          opk[p][qt][1] = pk2(o[2], o[3]);
        }
      }
    }
    __syncthreads();   // all waves done READING hbf (af) before flush
#pragma unroll
    for (int p = 0; p < 2; ++p) {
      const int hh = 4 * p + w;
#pragma unroll
      for (int qt = 0; qt < 2; ++qt) {
        u16* dst = hbf + (qt * 16 + gl * 4) * HBS + hh * 16 + l15;
        dst[0 * HBS] = (u16)opk[p][qt][0];
        dst[1 * HBS] = (u16)(opk[p][qt][0] >> 16);
        dst[2 * HBS] = (u16)opk[p][qt][1];
        dst[3 * HBS] = (u16)(opk[p][qt][1] >> 16);
      }
    }
    __syncthreads();

    // ---- proj: attn_out(bf16, hbf) @ Wo -> xs += ----
    {
      f32x4 acc[2][2];
      gemm_kt4_b<2>(hbf, oW, w, lane, bo_i, acc);
#pragma unroll
      for (int i = 0; i < 2; ++i) {
        int n = (w + 4 * i) * 16 + cr;
#pragma unroll
        for (int j = 0; j < 4; ++j) {
          xs[(rq + j) * LST + n]      += acc[i][0][j];
          xs[(rq + j + 16) * LST + n] += acc[i][1][j];
        }
      }
    }
    __syncthreads();

    layer_norm_bf(xs, hbf, a.ln2s + li * NE, a.ln2b + li * NE, t, mrow, vrow);

    // ---- MLP, 2 chunks of 256 cols ----
    {
      f32x4 acc2[2][2];
#pragma unroll
      for (int i = 0; i < 2; ++i) {
        float bb = bm2_i[(w + 4 * i) * 16 + cr];
        f32x4 bi = {bb, bb, bb, bb};
        acc2[i][0] = bi; acc2[i][1] = bi;
      }
#pragma unroll
      for (int ch = 0; ch < 2; ++ch) {
        {
          f32x4 acc[4][2];
          gemm_kt4_b<4>(hbf, m1W + ch * 32768, w, lane, bm1_i + ch * 256, acc);
#pragma unroll
          for (int i = 0; i < 4; ++i) {
            int nl = (w + 4 * i) * 16 + cr;
#pragma unroll
            for (int j = 0; j < 4; ++j) {
              h1c[(rq + j) * H1C + nl]      = f2b(gelu_f(acc[i][0][j]));
              h1c[(rq + j + 16) * H1C + nl] = f2b(gelu_f(acc[i][1][j]));
            }
          }
        }
        __syncthreads();
        gemm_kt8_acc(h1c, m2W, ch * 8, w, lane, acc2);
        __syncthreads();
      }
#pragma unroll
      for (int i = 0; i < 2; ++i) {
        int n = (w + 4 * i) * 16 + cr;
#pragma unroll
        for (int j = 0; j < 4; ++j) {
          xs[(rq + j) * LST + n]      += acc2[i][0][j];
          xs[(rq + j + 16) * LST + n] += acc2[i][1][j];
        }
      }
    }
    __syncthreads();
  }

  // ---- final LN -> hbf ----
  layer_norm_bf(xs, hbf, a.lnfs, a.lnfb, t, mrow, vrow);

  // preload Wd2 f32 (disjoint from h1c; ordered by the d1 barrier)
  for (int i = t; i < 1024; i += 256) wd2s[i] = a.Wd2[i];

  // ---- decoder, 2 chunks of 256 ----
  float yacc = 0.f;
  const int pdec = t >> 3, dd2 = (t >> 2) & 1, q4 = t & 3;
#pragma unroll
  for (int ch = 0; ch < 2; ++ch) {
    {
      f32x4 acc[4][2];
      gemm_kt4_b<4>(hbf, wsW + D1_W_OFF + ch * 32768, w, lane, a.bd1 + ch * 256, acc);
#pragma unroll
      for (int i = 0; i < 4; ++i) {
        int nl = (w + 4 * i) * 16 + cr;
#pragma unroll
        for (int j = 0; j < 4; ++j) {
          h1c[(rq + j) * H1C + nl]      = f2b(fmaxf(acc[i][0][j], 0.f));
          h1c[(rq + j + 16) * H1C + nl] = f2b(fmaxf(acc[i][1][j], 0.f));
        }
      }
    }
    __syncthreads();
    {
      const u16* hrow = h1c + pdec * H1C + q4 * 64;
      const float* wp = wd2s + (ch * 256 + q4 * 64) * 2 + dd2;
#pragma unroll
      for (int k8 = 0; k8 < 8; ++k8) {
        bf16x8 hv = *(const bf16x8*)(hrow + k8 * 8);
#pragma unroll
        for (int jj = 0; jj < 8; ++jj)
          yacc += b2f((u16)hv[jj]) * wp[(k8 * 8 + jj) * 2];
      }
    }
    __syncthreads();
  }

  // ---- y write + loss partial ----
  {
    yacc += __shfl_xor(yacc, 1);
    yacc += __shfl_xor(yacc, 2);
    if (q4 == 0) {
      float y = yacc + a.bd2[dd2];
      a.out[1 + (s * NP + pdec) * 2 + dd2] = y;
      float lnm = a.pos[(s * NP + pdec) * 2 + dd2] - (dd2 ? cy : cx);
      float d = y - lnm;
      if (selv[pdec] != 0) atomicAdd(&lacc, d * d);
    }
  }
  __syncthreads();
  if (t == 0) {
    atomicAdd(a.wsf, lacc);
    int cnt = 0;
#pragma unroll
    for (int p = 0; p < NP; ++p) cnt += (selv[p] != 0) ? 1 : 0;
    atomicAdd(a.wsi, cnt);
  }
}

__global__ void mrm_fin(const float* ws, float* out) {
  float num = ws[0];
  int cnt = ((const int*)ws)[1];
  float den = fmaxf((float)cnt * 2.0f, 1.0f);
  out[0] = num / den;
}

extern "C" void kernel_launch(void* const* d_in, const int* in_sizes, int n_in,
                              void* d_out, int out_size, void* d_ws, size_t ws_size,
                              hipStream_t stream) {
  (void)in_sizes; (void)n_in; (void)out_size; (void)ws_size;
  Args a;
  a.pos   = (const float*)d_in[0];
  a.ctr   = (const float*)d_in[1];
  a.ang   = (const float*)d_in[2];
  a.sel   = (const int*)d_in[4];
  a.Wp    = (const float*)d_in[5];
  a.bp    = (const float*)d_in[6];
  a.Wpe1  = (const float*)d_in[7];
  a.bpe1  = (const float*)d_in[8];
  a.Wpe2  = (const float*)d_in[9];
  a.bpe2  = (const float*)d_in[10];
  a.ltype = (const float*)d_in[11];
  a.mtok  = (const float*)d_in[12];
  a.Wqkv  = (const float*)d_in[13];
  a.bqkv  = (const float*)d_in[14];
  a.Wo    = (const float*)d_in[15];
  a.bo    = (const float*)d_in[16];
  a.ln1s  = (const float*)d_in[17];
  a.ln1b  = (const float*)d_in[18];
  a.Wm1   = (const float*)d_in[19];
  a.bm1   = (const float*)d_in[20];
  a.Wm2   = (const float*)d_in[21];
  a.bm2   = (const float*)d_in[22];
  a.ln2s  = (const float*)d_in[23];
  a.ln2b  = (const float*)d_in[24];
  a.lnfs  = (const float*)d_in[25];
  a.lnfb  = (const float*)d_in[26];
  a.Wd1   = (const float*)d_in[27];
  a.bd1   = (const float*)d_in[28];
  a.Wd2   = (const float*)d_in[29];
  a.bd2   = (const float*)d_in[30];
  a.out   = (float*)d_out;
  a.wsf   = (float*)d_ws;
  a.wsi   = ((int*)d_ws) + 1;

  hipMemsetAsync(d_ws, 0, 8, stream);
  u16* wsW = (u16*)((char*)d_ws + 64);
  pack_w<<<dim3(96),  dim3(256), 0, stream>>>(a.Wqkv, wsW + QKV_W_OFF, 128, 384, 4, 128, 0.25f);
  pack_w<<<dim3(32),  dim3(256), 0, stream>>>(a.Wo,   wsW + O_W_OFF,   128, 128, 4, 0, 1.f);
  pack_w<<<dim3(128), dim3(256), 0, stream>>>(a.Wm1,  wsW + M1_W_OFF,  128, 512, 4, 0, 1.f);
  pack_w<<<dim3(128), dim3(256), 0, stream>>>(a.Wm2,  wsW + M2_W_OFF,  512, 128, 4, 0, 1.f);
  pack_w<<<dim3(32),  dim3(256), 0, stream>>>(a.Wd1,  wsW + D1_W_OFF,  128, 512, 1, 0, 1.f);
  mrm_main_mfma<<<dim3(NSEQ), dim3(256), 0, stream>>>(a, wsW);
  mrm_fin<<<dim3(1), dim3(1), 0, stream>>>((const float*)d_ws, (float*)d_out);
}